// Round 1
// baseline (865.181 us; speedup 1.0000x reference)
//
#include <hip/hip_runtime.h>
#include <hip/hip_bf16.h>
#include <cstdint>

#define TK 2048      // tokens (2*1024)
#define HD 2048      // hidden
#define ID 1024      // intermediate
#define NE 16        // routed experts
#define NG 17        // groups incl shared expert (g==16)
#define TOPK 4
#define SLOTS (TK*TOPK)       // 8192 routed rows
#define ROWS_ALL (SLOTS+TK)   // 10240 incl shared
#define IH (ID*HD)            // 2,097,152 elems per expert matrix

typedef __attribute__((ext_vector_type(4))) float f32x4;
typedef __attribute__((ext_vector_type(8))) short s16x8;
typedef unsigned short u16;
typedef unsigned long long u64;

__device__ __forceinline__ u16 f2bf(float f){
  union { float f; uint32_t u; } v; v.f = f;
  uint32_t r = v.u + 0x7fffu + ((v.u >> 16) & 1u);  // RNE
  return (u16)(r >> 16);
}

// ---------------- small kernels ----------------

__global__ void k_zero_out(float* __restrict__ out, int n){
  int i = blockIdx.x*blockDim.x + threadIdx.x;
  int st = gridDim.x*blockDim.x;
  for (; i < n; i += st) out[i] = 0.f;
}

__global__ void k_init(u64* __restrict__ maskbits){
  int i = threadIdx.x;
  if (i < NE*32) maskbits[i] = 0ull;
}

__global__ void k_cvt(const float* __restrict__ in, u16* __restrict__ out, int n4){
  int i = blockIdx.x*blockDim.x + threadIdx.x;
  int st = gridDim.x*blockDim.x;
  for (; i < n4; i += st){
    float4 f = ((const float4*)in)[i];
    ushort4 o;
    o.x = f2bf(f.x); o.y = f2bf(f.y); o.z = f2bf(f.z); o.w = f2bf(f.w);
    ((ushort4*)out)[i] = o;
  }
}

// router logits: one block per token, fp32
__global__ __launch_bounds__(256) void k_logits(const float* __restrict__ x,
                                                const float* __restrict__ gw,
                                                float* __restrict__ logits){
  int t = blockIdx.x, tid = threadIdx.x;
  int lane = tid & 63, wv = tid >> 6;
  const float* xr = x + (size_t)t*HD;
  float acc[NE];
  #pragma unroll
  for (int e=0;e<NE;e++) acc[e]=0.f;
  for (int k=tid;k<HD;k+=256){
    float xv = xr[k];
    #pragma unroll
    for (int e=0;e<NE;e++) acc[e] += xv * gw[e*HD + k];
  }
  __shared__ float red[NE][4];
  #pragma unroll
  for (int e=0;e<NE;e++){
    float v = acc[e];
    #pragma unroll
    for (int off=32;off>0;off>>=1) v += __shfl_down(v, off, 64);
    if (lane==0) red[e][wv] = v;
  }
  __syncthreads();
  if (tid < NE) logits[t*NE + tid] = red[tid][0]+red[tid][1]+red[tid][2]+red[tid][3];
}

// sigmoid, top-4 by (score+bias), renormalized raw-score weights
__global__ void k_select(const float* __restrict__ logits, const float* __restrict__ bias,
                         float* __restrict__ wdense, u64* __restrict__ maskbits){
  int t = blockIdx.x*blockDim.x + threadIdx.x;
  if (t >= TK) return;
  float sc[NE], bs[NE];
  #pragma unroll
  for (int e=0;e<NE;e++){
    float l = logits[t*NE+e];
    float s = 1.f/(1.f+expf(-l));
    sc[e]=s; bs[e]=s+bias[e];
  }
  int idx[TOPK]; float wsum=0.f;
  unsigned used=0;
  for (int k=0;k<TOPK;k++){
    int best=0; float bv=-1e30f;
    for (int e=0;e<NE;e++) if (!((used>>e)&1u) && bs[e] > bv){ bv=bs[e]; best=e; }
    used |= 1u<<best; idx[k]=best; wsum += sc[best];
  }
  float inv = 1.f/wsum;
  for (int k=0;k<TOPK;k++){
    int e = idx[k];
    wdense[t*NE + e] = sc[e]*inv;
    atomicOr(&maskbits[e*32 + (t>>6)], 1ull << (t&63));
  }
}

// prefix sums (tiny, 1 thread — deterministic)
__global__ void k_scan(const u64* __restrict__ maskbits, int* __restrict__ counts,
                       int* __restrict__ offsets, int* __restrict__ wordpfx){
  int acc = 0;
  for (int e=0;e<NE;e++){
    int c = 0;
    for (int w=0;w<32;w++){ wordpfx[e*32+w] = c; c += __popcll(maskbits[e*32+w]); }
    counts[e] = c;
  }
  for (int e=0;e<NE;e++){ offsets[e] = acc; acc += counts[e]; }
  offsets[NE] = acc;   // == SLOTS
  counts[NE] = TK;     // shared expert
}

// deterministic compaction via popcount rank
__global__ void k_scatter(const u64* __restrict__ maskbits, const int* __restrict__ offsets,
                          const int* __restrict__ wordpfx, const float* __restrict__ wdense,
                          int* __restrict__ rowtok, float* __restrict__ roww){
  int t = blockIdx.x*blockDim.x + threadIdx.x;
  int e = blockIdx.y;
  if (t >= TK) return;
  if (e == NE){ rowtok[offsets[NE]+t] = t; roww[offsets[NE]+t] = 1.f; return; }
  u64 w = maskbits[e*32 + (t>>6)];
  if ((w >> (t&63)) & 1ull){
    int pos = offsets[e] + wordpfx[e*32 + (t>>6)] + __popcll(w & ((1ull << (t&63)) - 1ull));
    rowtok[pos] = t; roww[pos] = wdense[t*NE + e];
  }
}

// ---------------- grouped GEMM1: P = silu(X Wg^T) * (X Wu^T) * roww ----------------
// BM=128, BN=64 (of I), BK=32; 4 waves each own 64x32; dual accumulators (gate,up)
template<bool WB16>
__global__ __launch_bounds__(256) void k_gemm1(
    const u16* __restrict__ xb,
    const float* __restrict__ w_gate, const float* __restrict__ w_up,
    const float* __restrict__ sw_gate, const float* __restrict__ sw_up,
    const u16* __restrict__ wgb, const u16* __restrict__ wub,
    const int* __restrict__ counts, const int* __restrict__ offsets,
    const int* __restrict__ rowtok, const float* __restrict__ roww,
    u16* __restrict__ P)
{
  int g = blockIdx.z;
  int cnt = counts[g];
  int mt = blockIdx.x;
  if (mt*128 >= cnt) return;
  int n0 = blockIdx.y*64;
  int base = offsets[g];

  const float *wg32=nullptr, *wu32=nullptr;
  const u16 *wg16=nullptr, *wu16=nullptr;
  if (WB16){ wg16 = wgb + (size_t)g*IH; wu16 = wub + (size_t)g*IH; }
  else {
    wg32 = (g<NE) ? w_gate + (size_t)g*IH : sw_gate;
    wu32 = (g<NE) ? w_up   + (size_t)g*IH : sw_up;
  }

  __shared__ u16 lsA[128][40];
  __shared__ u16 lsG[64][40];
  __shared__ u16 lsU[64][40];

  int tid = threadIdx.x, lane = tid & 63, wv = tid >> 6;
  int wm = (wv>>1)*64, wn = (wv&1)*32;

  f32x4 accg[4][2] = {}; f32x4 accu[4][2] = {};

  int arow = tid>>1, ahalf = tid&1;
  int am = mt*128 + arow;
  const u16* aptr = nullptr;
  if (am < cnt){ int tok = rowtok[base + am]; aptr = xb + (size_t)tok*HD + 16*ahalf; }

  for (int k0=0; k0<HD; k0+=32){
    uint4 a0 = {0,0,0,0}, a1 = {0,0,0,0};
    if (aptr){ a0 = *(const uint4*)(aptr + k0); a1 = *(const uint4*)(aptr + k0 + 8); }
    *(uint4*)&lsA[arow][16*ahalf]   = a0;
    *(uint4*)&lsA[arow][16*ahalf+8] = a1;
    if (WB16){
      int mat = tid>>7, r = (tid>>1)&63, hf = tid&1;
      const u16* src = (mat ? wu16 : wg16) + (size_t)(n0+r)*HD + k0 + 16*hf;
      uint4 b0 = *(const uint4*)src, b1 = *(const uint4*)(src+8);
      if (mat){ *(uint4*)&lsU[r][16*hf]=b0; *(uint4*)&lsU[r][16*hf+8]=b1; }
      else    { *(uint4*)&lsG[r][16*hf]=b0; *(uint4*)&lsG[r][16*hf+8]=b1; }
    } else {
      int r = tid>>2, cg = tid&3;
      {
        const float* s = wg32 + (size_t)(n0+r)*HD + k0 + 8*cg;
        float4 f0 = *(const float4*)s, f1 = *(const float4*)(s+4);
        ushort4 o0, o1;
        o0.x=f2bf(f0.x); o0.y=f2bf(f0.y); o0.z=f2bf(f0.z); o0.w=f2bf(f0.w);
        o1.x=f2bf(f1.x); o1.y=f2bf(f1.y); o1.z=f2bf(f1.z); o1.w=f2bf(f1.w);
        *(ushort4*)&lsG[r][8*cg]   = o0;
        *(ushort4*)&lsG[r][8*cg+4] = o1;
      }
      {
        const float* s = wu32 + (size_t)(n0+r)*HD + k0 + 8*cg;
        float4 f0 = *(const float4*)s, f1 = *(const float4*)(s+4);
        ushort4 o0, o1;
        o0.x=f2bf(f0.x); o0.y=f2bf(f0.y); o0.z=f2bf(f0.z); o0.w=f2bf(f0.w);
        o1.x=f2bf(f1.x); o1.y=f2bf(f1.y); o1.z=f2bf(f1.z); o1.w=f2bf(f1.w);
        *(ushort4*)&lsU[r][8*cg]   = o0;
        *(ushort4*)&lsU[r][8*cg+4] = o1;
      }
    }
    __syncthreads();
    int kb = 8*(lane>>4), rl = lane&15;
    s16x8 af[4];
    #pragma unroll
    for (int mi=0;mi<4;mi++) af[mi] = *(const s16x8*)&lsA[wm+16*mi+rl][kb];
    #pragma unroll
    for (int ni=0;ni<2;ni++){
      s16x8 bg = *(const s16x8*)&lsG[wn+16*ni+rl][kb];
      s16x8 bu = *(const s16x8*)&lsU[wn+16*ni+rl][kb];
      #pragma unroll
      for (int mi=0;mi<4;mi++){
        accg[mi][ni] = __builtin_amdgcn_mfma_f32_16x16x32_bf16(af[mi], bg, accg[mi][ni], 0,0,0);
        accu[mi][ni] = __builtin_amdgcn_mfma_f32_16x16x32_bf16(af[mi], bu, accu[mi][ni], 0,0,0);
      }
    }
    __syncthreads();
  }
  // epilogue: SwiGLU * token weight -> bf16 P
  int rl4 = (lane>>4)*4, cl = lane&15;
  #pragma unroll
  for (int mi=0;mi<4;mi++){
    #pragma unroll
    for (int j=0;j<4;j++){
      int m = mt*128 + wm + mi*16 + rl4 + j;
      if (m < cnt){
        int slot = base + m;
        float wgt = roww[slot];
        #pragma unroll
        for (int ni=0;ni<2;ni++){
          float gv = accg[mi][ni][j], uv = accu[mi][ni][j];
          float pv = gv/(1.f+expf(-gv))*uv*wgt;
          P[(size_t)slot*ID + n0 + wn + ni*16 + cl] = f2bf(pv);
        }
      }
    }
  }
}

// ---------------- grouped GEMM2: out[tok] += P @ Wd^T ----------------
// BM=128, BN=128, BK=32; 4 waves each own 64x64
template<bool WB16>
__global__ __launch_bounds__(256) void k_gemm2(
    const u16* __restrict__ P,
    const float* __restrict__ w_down, const float* __restrict__ sw_down,
    const u16* __restrict__ wdb,
    const int* __restrict__ counts, const int* __restrict__ offsets,
    const int* __restrict__ rowtok, float* __restrict__ out)
{
  int g = blockIdx.z;
  int cnt = counts[g];
  int mt = blockIdx.x;
  if (mt*128 >= cnt) return;
  int n0 = blockIdx.y*128;
  int base = offsets[g];

  const float* wd32=nullptr; const u16* wd16=nullptr;
  if (WB16) wd16 = wdb + (size_t)g*IH;
  else      wd32 = (g<NE) ? w_down + (size_t)g*IH : sw_down;

  __shared__ u16 lsA[128][40];
  __shared__ u16 lsB[128][40];

  int tid = threadIdx.x, lane = tid & 63, wv = tid >> 6;
  int wm = (wv>>1)*64, wn = (wv&1)*64;
  f32x4 acc[4][4] = {};

  int arow = tid>>1, ahalf = tid&1;
  int am = mt*128 + arow;
  const u16* aptr = (am < cnt) ? P + (size_t)(base+am)*ID + 16*ahalf : nullptr;

  for (int k0=0; k0<ID; k0+=32){
    uint4 a0 = {0,0,0,0}, a1 = {0,0,0,0};
    if (aptr){ a0 = *(const uint4*)(aptr + k0); a1 = *(const uint4*)(aptr + k0 + 8); }
    *(uint4*)&lsA[arow][16*ahalf]   = a0;
    *(uint4*)&lsA[arow][16*ahalf+8] = a1;
    int r = tid>>1, hf = tid&1;
    if (WB16){
      const u16* s = wd16 + (size_t)(n0+r)*ID + k0 + 16*hf;
      uint4 b0 = *(const uint4*)s, b1 = *(const uint4*)(s+8);
      *(uint4*)&lsB[r][16*hf]   = b0;
      *(uint4*)&lsB[r][16*hf+8] = b1;
    } else {
      const float* s = wd32 + (size_t)(n0+r)*ID + k0 + 16*hf;
      float4 f0=*(const float4*)s, f1=*(const float4*)(s+4), f2=*(const float4*)(s+8), f3=*(const float4*)(s+12);
      ushort4 o0,o1,o2,o3;
      o0.x=f2bf(f0.x); o0.y=f2bf(f0.y); o0.z=f2bf(f0.z); o0.w=f2bf(f0.w);
      o1.x=f2bf(f1.x); o1.y=f2bf(f1.y); o1.z=f2bf(f1.z); o1.w=f2bf(f1.w);
      o2.x=f2bf(f2.x); o2.y=f2bf(f2.y); o2.z=f2bf(f2.z); o2.w=f2bf(f2.w);
      o3.x=f2bf(f3.x); o3.y=f2bf(f3.y); o3.z=f2bf(f3.z); o3.w=f2bf(f3.w);
      *(ushort4*)&lsB[r][16*hf]    = o0;
      *(ushort4*)&lsB[r][16*hf+4]  = o1;
      *(ushort4*)&lsB[r][16*hf+8]  = o2;
      *(ushort4*)&lsB[r][16*hf+12] = o3;
    }
    __syncthreads();
    int kb = 8*(lane>>4), rl = lane&15;
    s16x8 af[4], bfr[4];
    #pragma unroll
    for (int mi=0;mi<4;mi++) af[mi]  = *(const s16x8*)&lsA[wm+16*mi+rl][kb];
    #pragma unroll
    for (int ni=0;ni<4;ni++) bfr[ni] = *(const s16x8*)&lsB[wn+16*ni+rl][kb];
    #pragma unroll
    for (int mi=0;mi<4;mi++)
      #pragma unroll
      for (int ni=0;ni<4;ni++)
        acc[mi][ni] = __builtin_amdgcn_mfma_f32_16x16x32_bf16(af[mi], bfr[ni], acc[mi][ni], 0,0,0);
    __syncthreads();
  }
  int rl4 = (lane>>4)*4, cl = lane&15;
  #pragma unroll
  for (int mi=0;mi<4;mi++){
    #pragma unroll
    for (int j=0;j<4;j++){
      int m = mt*128 + wm + mi*16 + rl4 + j;
      if (m < cnt){
        int tok = rowtok[base + m];
        #pragma unroll
        for (int ni=0;ni<4;ni++)
          atomicAdd(&out[(size_t)tok*HD + n0 + wn + ni*16 + cl], acc[mi][ni][j]);
      }
    }
  }
}

// ---------------- host ----------------

extern "C" void kernel_launch(void* const* d_in, const int* in_sizes, int n_in,
                              void* d_out, int out_size, void* d_ws, size_t ws_size,
                              hipStream_t stream){
  (void)in_sizes; (void)n_in;
  const float* x       = (const float*)d_in[0];
  const float* gate_w  = (const float*)d_in[1];
  const float* ebias   = (const float*)d_in[2];
  const float* w_gate  = (const float*)d_in[3];
  const float* w_up    = (const float*)d_in[4];
  const float* w_down  = (const float*)d_in[5];
  const float* sw_gate = (const float*)d_in[6];
  const float* sw_up   = (const float*)d_in[7];
  const float* sw_down = (const float*)d_in[8];
  float* out = (float*)d_out;

  char* p = (char*)d_ws;
  auto alloc = [&](size_t bytes)->char*{ char* r = p; p += (bytes + 255) & ~(size_t)255; return r; };
  u16*   xb       = (u16*)  alloc((size_t)TK*HD*2);
  u16*   P        = (u16*)  alloc((size_t)ROWS_ALL*ID*2);
  float* logits   = (float*)alloc((size_t)TK*NE*4);
  float* wdense   = (float*)alloc((size_t)TK*NE*4);
  u64*   maskbits = (u64*)  alloc((size_t)NE*32*8);
  int*   wordpfx  = (int*)  alloc((size_t)NE*32*4);
  int*   counts   = (int*)  alloc(64);
  int*   offsets  = (int*)  alloc(64);
  int*   rowtok   = (int*)  alloc((size_t)ROWS_ALL*4);
  float* roww     = (float*)alloc((size_t)ROWS_ALL*4);
  size_t base_end = (size_t)(p - (char*)d_ws);
  size_t slab = (size_t)NG*IH*2;
  bool big = ws_size >= base_end + 3*slab + 4096;
  u16 *wgb=nullptr, *wub=nullptr, *wdb=nullptr;
  if (big){ wgb=(u16*)alloc(slab); wub=(u16*)alloc(slab); wdb=(u16*)alloc(slab); }

  k_init<<<1, 512, 0, stream>>>(maskbits);
  k_cvt<<<1024, 256, 0, stream>>>(x, xb, TK*HD/4);
  if (big){
    k_cvt<<<2048, 256, 0, stream>>>(w_gate,  wgb,                 NE*IH/4);
    k_cvt<<<256,  256, 0, stream>>>(sw_gate, wgb + (size_t)NE*IH, IH/4);
    k_cvt<<<2048, 256, 0, stream>>>(w_up,    wub,                 NE*IH/4);
    k_cvt<<<256,  256, 0, stream>>>(sw_up,   wub + (size_t)NE*IH, IH/4);
    k_cvt<<<2048, 256, 0, stream>>>(w_down,  wdb,                 NE*IH/4);
    k_cvt<<<256,  256, 0, stream>>>(sw_down, wdb + (size_t)NE*IH, IH/4);
  }
  k_logits<<<TK, 256, 0, stream>>>(x, gate_w, logits);
  k_select<<<TK/256, 256, 0, stream>>>(logits, ebias, wdense, maskbits);
  k_scan<<<1, 1, 0, stream>>>(maskbits, counts, offsets, wordpfx);
  k_scatter<<<dim3(TK/256, NG), 256, 0, stream>>>(maskbits, offsets, wordpfx, wdense, rowtok, roww);
  k_zero_out<<<2048, 256, 0, stream>>>(out, out_size);

  dim3 g1(TK/128, ID/64, NG);
  dim3 g2(TK/128, HD/128, NG);
  if (big){
    k_gemm1<true ><<<g1, 256, 0, stream>>>(xb, w_gate, w_up, sw_gate, sw_up, wgb, wub,
                                           counts, offsets, rowtok, roww, P);
    k_gemm2<true ><<<g2, 256, 0, stream>>>(P, w_down, sw_down, wdb, counts, offsets, rowtok, out);
  } else {
    k_gemm1<false><<<g1, 256, 0, stream>>>(xb, w_gate, w_up, sw_gate, sw_up, nullptr, nullptr,
                                           counts, offsets, rowtok, roww, P);
    k_gemm2<false><<<g2, 256, 0, stream>>>(P, w_down, sw_down, nullptr, counts, offsets, rowtok, out);
  }
}

// Round 2
// 784.801 us; speedup vs baseline: 1.1024x; 1.1024x over previous
//
#include <hip/hip_runtime.h>
#include <hip/hip_bf16.h>
#include <cstdint>

#define TK 2048      // tokens (2*1024)
#define HD 2048      // hidden
#define ID 1024      // intermediate
#define NE 16        // routed experts
#define NG 17        // groups incl shared expert (g==16)
#define TOPK 4
#define SLOTS (TK*TOPK)       // 8192 routed rows
#define ROWS_ALL (SLOTS+TK)   // 10240 incl shared
#define IH (ID*HD)            // 2,097,152 elems per expert matrix

typedef __attribute__((ext_vector_type(4))) float f32x4;
typedef __attribute__((ext_vector_type(8))) short s16x8;
typedef unsigned short u16;
typedef unsigned long long u64;

__device__ __forceinline__ u16 f2bf(float f){
  union { float f; uint32_t u; } v; v.f = f;
  uint32_t r = v.u + 0x7fffu + ((v.u >> 16) & 1u);  // RNE
  return (u16)(r >> 16);
}

// async global->LDS, 16B per lane; LDS dest is wave-uniform base + lane*16
#define GLD16(g, l) __builtin_amdgcn_global_load_lds( \
    (const __attribute__((address_space(1))) void*)(g), \
    (__attribute__((address_space(3))) void*)(l), 16, 0, 0)

// swizzled fragment pointer: 128B rows, byte ^= ((row&7)<<4)
__device__ __forceinline__ const s16x8* fragp(const u16* b, int row, int off){
  return (const s16x8*)((const char*)b + row*128 + (off ^ ((row&7)<<4)));
}

// ---------------- prep: zero out, init maskbits, convert x ----------------
__global__ void k_prep(const float* __restrict__ x, u16* __restrict__ xb,
                       float* __restrict__ out, int out_n, u64* __restrict__ maskbits){
  int gi = blockIdx.x*blockDim.x + threadIdx.x;
  int st = gridDim.x*blockDim.x;
  if (gi < NE*32) maskbits[gi] = 0ull;
  for (int i=gi; i<out_n; i+=st) out[i] = 0.f;
  for (int i=gi; i<TK*HD/4; i+=st){
    float4 f = ((const float4*)x)[i];
    ushort4 o; o.x=f2bf(f.x); o.y=f2bf(f.y); o.z=f2bf(f.z); o.w=f2bf(f.w);
    ((ushort4*)xb)[i] = o;
  }
}

// ---------------- convert all weights fp32 -> bf16 (one kernel) ----------------
__global__ void k_cvtw(const float* __restrict__ wg, const float* __restrict__ wu,
                       const float* __restrict__ wd, const float* __restrict__ swg,
                       const float* __restrict__ swu, const float* __restrict__ swd,
                       u16* __restrict__ wgb, u16* __restrict__ wub, u16* __restrict__ wdb){
  const size_t nbig = (size_t)NE*IH/4, nsml = IH/4;
  const size_t total = 3*nbig + 3*nsml;
  for (size_t i = (size_t)blockIdx.x*blockDim.x + threadIdx.x; i < total;
       i += (size_t)gridDim.x*blockDim.x){
    const float4* src; ushort4* dst; size_t j = i;
    if (j < nbig){ src=(const float4*)wg + j;  dst=(ushort4*)wgb + j; }
    else if ((j-=nbig) < nbig){ src=(const float4*)wu + j;  dst=(ushort4*)wub + j; }
    else if ((j-=nbig) < nbig){ src=(const float4*)wd + j;  dst=(ushort4*)wdb + j; }
    else if ((j-=nbig) < nsml){ src=(const float4*)swg + j; dst=(ushort4*)wgb + nbig + j; }
    else if ((j-=nsml) < nsml){ src=(const float4*)swu + j; dst=(ushort4*)wub + nbig + j; }
    else { j-=nsml; src=(const float4*)swd + j; dst=(ushort4*)wdb + nbig + j; }
    float4 f = *src;
    ushort4 o; o.x=f2bf(f.x); o.y=f2bf(f.y); o.z=f2bf(f.z); o.w=f2bf(f.w);
    *dst = o;
  }
}

// ---------------- router: logits + sigmoid + top-4 select (fused) ----------------
__global__ __launch_bounds__(256) void k_logits(const float* __restrict__ x,
                                                const float* __restrict__ gw,
                                                const float* __restrict__ bias,
                                                float* __restrict__ wdense,
                                                u64* __restrict__ maskbits){
  int t = blockIdx.x, tid = threadIdx.x;
  int lane = tid & 63, wv = tid >> 6;
  const float* xr = x + (size_t)t*HD;
  float acc[NE];
  #pragma unroll
  for (int e=0;e<NE;e++) acc[e]=0.f;
  for (int k=tid;k<HD;k+=256){
    float xv = xr[k];
    #pragma unroll
    for (int e=0;e<NE;e++) acc[e] += xv * gw[e*HD + k];
  }
  __shared__ float red[NE][4];
  #pragma unroll
  for (int e=0;e<NE;e++){
    float v = acc[e];
    #pragma unroll
    for (int off=32;off>0;off>>=1) v += __shfl_down(v, off, 64);
    if (lane==0) red[e][wv] = v;
  }
  __syncthreads();
  if (tid == 0){
    float sc[NE], bs[NE];
    #pragma unroll
    for (int e=0;e<NE;e++){
      float l = red[e][0]+red[e][1]+red[e][2]+red[e][3];
      float s = 1.f/(1.f+expf(-l));
      sc[e]=s; bs[e]=s+bias[e];
    }
    int idx[TOPK]; float wsum=0.f; unsigned used=0;
    for (int k=0;k<TOPK;k++){
      int best=0; float bv=-1e30f;
      for (int e=0;e<NE;e++) if (!((used>>e)&1u) && bs[e] > bv){ bv=bs[e]; best=e; }
      used |= 1u<<best; idx[k]=best; wsum += sc[best];
    }
    float inv = 1.f/wsum;
    for (int k=0;k<TOPK;k++){
      int e = idx[k];
      wdense[t*NE + e] = sc[e]*inv;
      atomicOr(&maskbits[e*32 + (t>>6)], 1ull << (t&63));
    }
  }
}

// prefix sums (tiny, 1 thread — deterministic)
__global__ void k_scan(const u64* __restrict__ maskbits, int* __restrict__ counts,
                       int* __restrict__ offsets, int* __restrict__ wordpfx){
  int acc = 0;
  for (int e=0;e<NE;e++){
    int c = 0;
    for (int w=0;w<32;w++){ wordpfx[e*32+w] = c; c += __popcll(maskbits[e*32+w]); }
    counts[e] = c;
  }
  for (int e=0;e<NE;e++){ offsets[e] = acc; acc += counts[e]; }
  offsets[NE] = acc;   // == SLOTS
  counts[NE] = TK;     // shared expert
}

// deterministic compaction via popcount rank
__global__ void k_scatter(const u64* __restrict__ maskbits, const int* __restrict__ offsets,
                          const int* __restrict__ wordpfx, const float* __restrict__ wdense,
                          int* __restrict__ rowtok, float* __restrict__ roww){
  int t = blockIdx.x*blockDim.x + threadIdx.x;
  int e = blockIdx.y;
  if (t >= TK) return;
  if (e == NE){ rowtok[offsets[NE]+t] = t; roww[offsets[NE]+t] = 1.f; return; }
  u64 w = maskbits[e*32 + (t>>6)];
  if ((w >> (t&63)) & 1ull){
    int pos = offsets[e] + wordpfx[e*32 + (t>>6)] + __popcll(w & ((1ull << (t&63)) - 1ull));
    rowtok[pos] = t; roww[pos] = wdense[t*NE + e];
  }
}

// ============ GEMM1 (bf16 weights): P = silu(X Wg^T)*(X Wu^T)*roww ============
// BM=128, BN=64 (gate+up), BK=64; global_load_lds staging, swizzled LDS
__global__ __launch_bounds__(256) void k_gemm1b(
    const u16* __restrict__ xb, const u16* __restrict__ wgb, const u16* __restrict__ wub,
    const int* __restrict__ counts, const int* __restrict__ offsets,
    const int* __restrict__ rowtok, const float* __restrict__ roww,
    u16* __restrict__ P)
{
  int g = blockIdx.z;
  int cnt = counts[g];
  int mt = blockIdx.x;
  if (mt*128 >= cnt) return;
  int n0 = blockIdx.y*64;
  int base = offsets[g];
  const u16* wg16 = wgb + (size_t)g*IH;
  const u16* wu16 = wub + (size_t)g*IH;

  __shared__ u16 lsA[128*64];
  __shared__ u16 lsG[64*64];
  __shared__ u16 lsU[64*64];

  int tid = threadIdx.x, lane = tid & 63, wv = tid >> 6;
  int wm = (wv>>1)*64, wn = (wv&1)*32;
  int rl = lane & 15, hi = lane >> 4;

  f32x4 accg[4][2] = {}; f32x4 accu[4][2] = {};

  // staging descriptors (source pre-swizzled: col block = cb ^ (r&7))
  const u16* aSrc[4];
  #pragma unroll
  for (int i=0;i<4;i++){
    int b = i*256 + tid, r = b>>3, cb = b&7;
    int m = mt*128 + r; if (m >= cnt) m = cnt-1;
    int tok = rowtok[base + m];
    aSrc[i] = xb + (size_t)tok*HD + ((cb ^ (r&7))<<3);
  }
  const u16 *gSrc[2], *uSrc[2];
  #pragma unroll
  for (int i=0;i<2;i++){
    int b = i*256 + tid, r = b>>3, cb = b&7;
    size_t off = (size_t)(n0 + r)*HD + ((cb ^ (r&7))<<3);
    gSrc[i] = wg16 + off; uSrc[i] = wu16 + off;
  }

  for (int k0=0; k0<HD; k0+=64){
    #pragma unroll
    for (int i=0;i<4;i++) GLD16(aSrc[i]+k0, lsA + (i*256 + wv*64)*8);
    #pragma unroll
    for (int i=0;i<2;i++) GLD16(gSrc[i]+k0, lsG + (i*256 + wv*64)*8);
    #pragma unroll
    for (int i=0;i<2;i++) GLD16(uSrc[i]+k0, lsU + (i*256 + wv*64)*8);
    __syncthreads();
    #pragma unroll
    for (int ks=0; ks<2; ++ks){
      int off = ks*64 + hi*16;
      s16x8 af[4];
      #pragma unroll
      for (int mi=0;mi<4;mi++) af[mi] = *fragp(lsA, wm+16*mi+rl, off);
      #pragma unroll
      for (int ni=0;ni<2;ni++){
        s16x8 bg = *fragp(lsG, wn+16*ni+rl, off);
        s16x8 bu = *fragp(lsU, wn+16*ni+rl, off);
        #pragma unroll
        for (int mi=0;mi<4;mi++){
          accg[mi][ni] = __builtin_amdgcn_mfma_f32_16x16x32_bf16(af[mi], bg, accg[mi][ni], 0,0,0);
          accu[mi][ni] = __builtin_amdgcn_mfma_f32_16x16x32_bf16(af[mi], bu, accu[mi][ni], 0,0,0);
        }
      }
    }
    __syncthreads();
  }
  // epilogue: SwiGLU * token weight -> bf16 P
  int rl4 = hi*4, cl = rl;
  #pragma unroll
  for (int mi=0;mi<4;mi++){
    #pragma unroll
    for (int j=0;j<4;j++){
      int m = mt*128 + wm + mi*16 + rl4 + j;
      if (m < cnt){
        int slot = base + m;
        float wgt = roww[slot];
        #pragma unroll
        for (int ni=0;ni<2;ni++){
          float gv = accg[mi][ni][j], uv = accu[mi][ni][j];
          float pv = gv/(1.f+expf(-gv))*uv*wgt;
          P[(size_t)slot*ID + n0 + wn + ni*16 + cl] = f2bf(pv);
        }
      }
    }
  }
}

// ============ GEMM2 (bf16 weights): out[tok] += P @ Wd^T ============
// BM=128, BN=128, BK=64
__global__ __launch_bounds__(256) void k_gemm2b(
    const u16* __restrict__ P, const u16* __restrict__ wdb,
    const int* __restrict__ counts, const int* __restrict__ offsets,
    const int* __restrict__ rowtok, float* __restrict__ out)
{
  int g = blockIdx.z;
  int cnt = counts[g];
  int mt = blockIdx.x;
  if (mt*128 >= cnt) return;
  int n0 = blockIdx.y*128;
  int base = offsets[g];
  const u16* wd16 = wdb + (size_t)g*IH;

  __shared__ u16 lsA[128*64];
  __shared__ u16 lsB[128*64];

  int tid = threadIdx.x, lane = tid & 63, wv = tid >> 6;
  int wm = (wv>>1)*64, wn = (wv&1)*64;
  int rl = lane & 15, hi = lane >> 4;
  f32x4 acc[4][4] = {};

  const u16 *aSrc[4], *bSrc[4];
  #pragma unroll
  for (int i=0;i<4;i++){
    int b = i*256 + tid, r = b>>3, cb = b&7;
    int m = mt*128 + r; if (m >= cnt) m = cnt-1;
    aSrc[i] = P + (size_t)(base + m)*ID + ((cb ^ (r&7))<<3);
    bSrc[i] = wd16 + (size_t)(n0 + r)*ID + ((cb ^ (r&7))<<3);
  }

  for (int k0=0; k0<ID; k0+=64){
    #pragma unroll
    for (int i=0;i<4;i++) GLD16(aSrc[i]+k0, lsA + (i*256 + wv*64)*8);
    #pragma unroll
    for (int i=0;i<4;i++) GLD16(bSrc[i]+k0, lsB + (i*256 + wv*64)*8);
    __syncthreads();
    #pragma unroll
    for (int ks=0; ks<2; ++ks){
      int off = ks*64 + hi*16;
      s16x8 af[4], bf[4];
      #pragma unroll
      for (int mi=0;mi<4;mi++) af[mi] = *fragp(lsA, wm+16*mi+rl, off);
      #pragma unroll
      for (int ni=0;ni<4;ni++) bf[ni] = *fragp(lsB, wn+16*ni+rl, off);
      #pragma unroll
      for (int mi=0;mi<4;mi++)
        #pragma unroll
        for (int ni=0;ni<4;ni++)
          acc[mi][ni] = __builtin_amdgcn_mfma_f32_16x16x32_bf16(af[mi], bf[ni], acc[mi][ni], 0,0,0);
    }
    __syncthreads();
  }
  int rl4 = hi*4, cl = rl;
  #pragma unroll
  for (int mi=0;mi<4;mi++){
    #pragma unroll
    for (int j=0;j<4;j++){
      int m = mt*128 + wm + mi*16 + rl4 + j;
      if (m < cnt){
        int tok = rowtok[base + m];
        #pragma unroll
        for (int ni=0;ni<4;ni++)
          atomicAdd(&out[(size_t)tok*HD + n0 + wn + ni*16 + cl], acc[mi][ni][j]);
      }
    }
  }
}

// ============ fallback kernels (fp32 weights, small ws) ============
__global__ __launch_bounds__(256) void k_gemm1o(
    const u16* __restrict__ xb,
    const float* __restrict__ w_gate, const float* __restrict__ w_up,
    const float* __restrict__ sw_gate, const float* __restrict__ sw_up,
    const int* __restrict__ counts, const int* __restrict__ offsets,
    const int* __restrict__ rowtok, const float* __restrict__ roww,
    u16* __restrict__ P)
{
  int g = blockIdx.z;
  int cnt = counts[g];
  int mt = blockIdx.x;
  if (mt*128 >= cnt) return;
  int n0 = blockIdx.y*64;
  int base = offsets[g];
  const float* wg32 = (g<NE) ? w_gate + (size_t)g*IH : sw_gate;
  const float* wu32 = (g<NE) ? w_up   + (size_t)g*IH : sw_up;

  __shared__ u16 lsA[128][40];
  __shared__ u16 lsG[64][40];
  __shared__ u16 lsU[64][40];

  int tid = threadIdx.x, lane = tid & 63, wv = tid >> 6;
  int wm = (wv>>1)*64, wn = (wv&1)*32;
  f32x4 accg[4][2] = {}; f32x4 accu[4][2] = {};
  int arow = tid>>1, ahalf = tid&1;
  int am = mt*128 + arow;
  const u16* aptr = nullptr;
  if (am < cnt){ int tok = rowtok[base + am]; aptr = xb + (size_t)tok*HD + 16*ahalf; }

  for (int k0=0; k0<HD; k0+=32){
    uint4 a0 = {0,0,0,0}, a1 = {0,0,0,0};
    if (aptr){ a0 = *(const uint4*)(aptr + k0); a1 = *(const uint4*)(aptr + k0 + 8); }
    *(uint4*)&lsA[arow][16*ahalf]   = a0;
    *(uint4*)&lsA[arow][16*ahalf+8] = a1;
    int r = tid>>2, cg = tid&3;
    {
      const float* s = wg32 + (size_t)(n0+r)*HD + k0 + 8*cg;
      float4 f0 = *(const float4*)s, f1 = *(const float4*)(s+4);
      ushort4 o0, o1;
      o0.x=f2bf(f0.x); o0.y=f2bf(f0.y); o0.z=f2bf(f0.z); o0.w=f2bf(f0.w);
      o1.x=f2bf(f1.x); o1.y=f2bf(f1.y); o1.z=f2bf(f1.z); o1.w=f2bf(f1.w);
      *(ushort4*)&lsG[r][8*cg]   = o0;
      *(ushort4*)&lsG[r][8*cg+4] = o1;
    }
    {
      const float* s = wu32 + (size_t)(n0+r)*HD + k0 + 8*cg;
      float4 f0 = *(const float4*)s, f1 = *(const float4*)(s+4);
      ushort4 o0, o1;
      o0.x=f2bf(f0.x); o0.y=f2bf(f0.y); o0.z=f2bf(f0.z); o0.w=f2bf(f0.w);
      o1.x=f2bf(f1.x); o1.y=f2bf(f1.y); o1.z=f2bf(f1.z); o1.w=f2bf(f1.w);
      *(ushort4*)&lsU[r][8*cg]   = o0;
      *(ushort4*)&lsU[r][8*cg+4] = o1;
    }
    __syncthreads();
    int kb = 8*(lane>>4), rl = lane&15;
    s16x8 af[4];
    #pragma unroll
    for (int mi=0;mi<4;mi++) af[mi] = *(const s16x8*)&lsA[wm+16*mi+rl][kb];
    #pragma unroll
    for (int ni=0;ni<2;ni++){
      s16x8 bg = *(const s16x8*)&lsG[wn+16*ni+rl][kb];
      s16x8 bu = *(const s16x8*)&lsU[wn+16*ni+rl][kb];
      #pragma unroll
      for (int mi=0;mi<4;mi++){
        accg[mi][ni] = __builtin_amdgcn_mfma_f32_16x16x32_bf16(af[mi], bg, accg[mi][ni], 0,0,0);
        accu[mi][ni] = __builtin_amdgcn_mfma_f32_16x16x32_bf16(af[mi], bu, accu[mi][ni], 0,0,0);
      }
    }
    __syncthreads();
  }
  int rl4 = (lane>>4)*4, cl = lane&15;
  #pragma unroll
  for (int mi=0;mi<4;mi++){
    #pragma unroll
    for (int j=0;j<4;j++){
      int m = mt*128 + wm + mi*16 + rl4 + j;
      if (m < cnt){
        int slot = base + m;
        float wgt = roww[slot];
        #pragma unroll
        for (int ni=0;ni<2;ni++){
          float gv = accg[mi][ni][j], uv = accu[mi][ni][j];
          float pv = gv/(1.f+expf(-gv))*uv*wgt;
          P[(size_t)slot*ID + n0 + wn + ni*16 + cl] = f2bf(pv);
        }
      }
    }
  }
}

__global__ __launch_bounds__(256) void k_gemm2o(
    const u16* __restrict__ P,
    const float* __restrict__ w_down, const float* __restrict__ sw_down,
    const int* __restrict__ counts, const int* __restrict__ offsets,
    const int* __restrict__ rowtok, float* __restrict__ out)
{
  int g = blockIdx.z;
  int cnt = counts[g];
  int mt = blockIdx.x;
  if (mt*128 >= cnt) return;
  int n0 = blockIdx.y*128;
  int base = offsets[g];
  const float* wd32 = (g<NE) ? w_down + (size_t)g*IH : sw_down;

  __shared__ u16 lsA[128][40];
  __shared__ u16 lsB[128][40];

  int tid = threadIdx.x, lane = tid & 63, wv = tid >> 6;
  int wm = (wv>>1)*64, wn = (wv&1)*64;
  f32x4 acc[4][4] = {};
  int arow = tid>>1, ahalf = tid&1;
  int am = mt*128 + arow;
  const u16* aptr = (am < cnt) ? P + (size_t)(base+am)*ID + 16*ahalf : nullptr;

  for (int k0=0; k0<ID; k0+=32){
    uint4 a0 = {0,0,0,0}, a1 = {0,0,0,0};
    if (aptr){ a0 = *(const uint4*)(aptr + k0); a1 = *(const uint4*)(aptr + k0 + 8); }
    *(uint4*)&lsA[arow][16*ahalf]   = a0;
    *(uint4*)&lsA[arow][16*ahalf+8] = a1;
    int r = tid>>1, hf = tid&1;
    const float* s = wd32 + (size_t)(n0+r)*ID + k0 + 16*hf;
    float4 f0=*(const float4*)s, f1=*(const float4*)(s+4), f2=*(const float4*)(s+8), f3=*(const float4*)(s+12);
    ushort4 o0,o1,o2,o3;
    o0.x=f2bf(f0.x); o0.y=f2bf(f0.y); o0.z=f2bf(f0.z); o0.w=f2bf(f0.w);
    o1.x=f2bf(f1.x); o1.y=f2bf(f1.y); o1.z=f2bf(f1.z); o1.w=f2bf(f1.w);
    o2.x=f2bf(f2.x); o2.y=f2bf(f2.y); o2.z=f2bf(f2.z); o2.w=f2bf(f2.w);
    o3.x=f2bf(f3.x); o3.y=f2bf(f3.y); o3.z=f2bf(f3.z); o3.w=f2bf(f3.w);
    *(ushort4*)&lsB[r][16*hf]    = o0;
    *(ushort4*)&lsB[r][16*hf+4]  = o1;
    *(ushort4*)&lsB[r][16*hf+8]  = o2;
    *(ushort4*)&lsB[r][16*hf+12] = o3;
    __syncthreads();
    int kb = 8*(lane>>4), rl = lane&15;
    s16x8 af[4], bfr[4];
    #pragma unroll
    for (int mi=0;mi<4;mi++) af[mi]  = *(const s16x8*)&lsA[wm+16*mi+rl][kb];
    #pragma unroll
    for (int ni=0;ni<4;ni++) bfr[ni] = *(const s16x8*)&lsB[wn+16*ni+rl][kb];
    #pragma unroll
    for (int mi=0;mi<4;mi++)
      #pragma unroll
      for (int ni=0;ni<4;ni++)
        acc[mi][ni] = __builtin_amdgcn_mfma_f32_16x16x32_bf16(af[mi], bfr[ni], acc[mi][ni], 0,0,0);
    __syncthreads();
  }
  int rl4 = (lane>>4)*4, cl = lane&15;
  #pragma unroll
  for (int mi=0;mi<4;mi++){
    #pragma unroll
    for (int j=0;j<4;j++){
      int m = mt*128 + wm + mi*16 + rl4 + j;
      if (m < cnt){
        int tok = rowtok[base + m];
        #pragma unroll
        for (int ni=0;ni<4;ni++)
          atomicAdd(&out[(size_t)tok*HD + n0 + wn + ni*16 + cl], acc[mi][ni][j]);
      }
    }
  }
}

// ---------------- host ----------------

extern "C" void kernel_launch(void* const* d_in, const int* in_sizes, int n_in,
                              void* d_out, int out_size, void* d_ws, size_t ws_size,
                              hipStream_t stream){
  (void)in_sizes; (void)n_in;
  const float* x       = (const float*)d_in[0];
  const float* gate_w  = (const float*)d_in[1];
  const float* ebias   = (const float*)d_in[2];
  const float* w_gate  = (const float*)d_in[3];
  const float* w_up    = (const float*)d_in[4];
  const float* w_down  = (const float*)d_in[5];
  const float* sw_gate = (const float*)d_in[6];
  const float* sw_up   = (const float*)d_in[7];
  const float* sw_down = (const float*)d_in[8];
  float* out = (float*)d_out;

  char* p = (char*)d_ws;
  auto alloc = [&](size_t bytes)->char*{ char* r = p; p += (bytes + 255) & ~(size_t)255; return r; };
  u16*   xb       = (u16*)  alloc((size_t)TK*HD*2);
  u16*   P        = (u16*)  alloc((size_t)ROWS_ALL*ID*2);
  float* wdense   = (float*)alloc((size_t)TK*NE*4);
  u64*   maskbits = (u64*)  alloc((size_t)NE*32*8);
  int*   wordpfx  = (int*)  alloc((size_t)NE*32*4);
  int*   counts   = (int*)  alloc(64);
  int*   offsets  = (int*)  alloc(64);
  int*   rowtok   = (int*)  alloc((size_t)ROWS_ALL*4);
  float* roww     = (float*)alloc((size_t)ROWS_ALL*4);
  size_t base_end = (size_t)(p - (char*)d_ws);
  size_t slab = (size_t)NG*IH*2;
  bool big = ws_size >= base_end + 3*slab + 4096;
  u16 *wgb=nullptr, *wub=nullptr, *wdb=nullptr;
  if (big){ wgb=(u16*)alloc(slab); wub=(u16*)alloc(slab); wdb=(u16*)alloc(slab); }

  k_prep<<<2048, 256, 0, stream>>>(x, xb, out, out_size, maskbits);
  if (big)
    k_cvtw<<<2048, 256, 0, stream>>>(w_gate, w_up, w_down, sw_gate, sw_up, sw_down,
                                     wgb, wub, wdb);
  k_logits<<<TK, 256, 0, stream>>>(x, gate_w, ebias, wdense, maskbits);
  k_scan<<<1, 1, 0, stream>>>(maskbits, counts, offsets, wordpfx);
  k_scatter<<<dim3(TK/256, NG), 256, 0, stream>>>(maskbits, offsets, wordpfx, wdense, rowtok, roww);

  dim3 g1(TK/128, ID/64, NG);
  dim3 g2(TK/128, HD/128, NG);
  if (big){
    k_gemm1b<<<g1, 256, 0, stream>>>(xb, wgb, wub, counts, offsets, rowtok, roww, P);
    k_gemm2b<<<g2, 256, 0, stream>>>(P, wdb, counts, offsets, rowtok, out);
  } else {
    k_gemm1o<<<g1, 256, 0, stream>>>(xb, w_gate, w_up, sw_gate, sw_up,
                                     counts, offsets, rowtok, roww, P);
    k_gemm2o<<<g2, 256, 0, stream>>>(P, w_down, sw_down, counts, offsets, rowtok, out);
  }
}

// Round 3
// 428.883 us; speedup vs baseline: 2.0173x; 1.8299x over previous
//
#include <hip/hip_runtime.h>
#include <hip/hip_bf16.h>
#include <cstdint>

#define TK 2048      // tokens (2*1024)
#define HD 2048      // hidden
#define ID 1024      // intermediate
#define NE 16        // routed experts
#define NG 17        // groups incl shared expert (g==16)
#define TOPK 4
#define SLOTS (TK*TOPK)       // 8192 routed rows
#define ROWS_ALL (SLOTS+TK)   // 10240 incl shared
#define IH (ID*HD)            // 2,097,152 elems per expert matrix
#define MAXT 96               // max M-tiles across all groups (64+16 routed + 16 shared)

typedef __attribute__((ext_vector_type(4))) float f32x4;
typedef __attribute__((ext_vector_type(8))) short s16x8;
typedef unsigned short u16;
typedef unsigned long long u64;

__device__ __forceinline__ u16 f2bf(float f){
  union { float f; uint32_t u; } v; v.f = f;
  uint32_t r = v.u + 0x7fffu + ((v.u >> 16) & 1u);  // RNE
  return (u16)(r >> 16);
}

// async global->LDS, 16B per lane; LDS dest is wave-uniform base + lane*16
#define GLD16(g, l) __builtin_amdgcn_global_load_lds( \
    (const __attribute__((address_space(1))) void*)(g), \
    (__attribute__((address_space(3))) void*)(l), 16, 0, 0)

// swizzled fragment pointer: 128B rows, byte ^= ((row&7)<<4)
__device__ __forceinline__ const s16x8* fragp(const u16* b, int row, int off){
  return (const s16x8*)((const char*)b + row*128 + (off ^ ((row&7)<<4)));
}

// ---------------- prep: zero out, init maskbits, convert x ----------------
__global__ void k_prep(const float* __restrict__ x, u16* __restrict__ xb,
                       float* __restrict__ out, int out_n, u64* __restrict__ maskbits){
  int gi = blockIdx.x*blockDim.x + threadIdx.x;
  int st = gridDim.x*blockDim.x;
  if (gi < NE*32) maskbits[gi] = 0ull;
  for (int i=gi; i<out_n; i+=st) out[i] = 0.f;
  for (int i=gi; i<TK*HD/4; i+=st){
    float4 f = ((const float4*)x)[i];
    ushort4 o; o.x=f2bf(f.x); o.y=f2bf(f.y); o.z=f2bf(f.z); o.w=f2bf(f.w);
    ((ushort4*)xb)[i] = o;
  }
}

// ---------------- convert all weights fp32 -> bf16 (one kernel) ----------------
__global__ void k_cvtw(const float* __restrict__ wg, const float* __restrict__ wu,
                       const float* __restrict__ wd, const float* __restrict__ swg,
                       const float* __restrict__ swu, const float* __restrict__ swd,
                       u16* __restrict__ wgb, u16* __restrict__ wub, u16* __restrict__ wdb){
  const size_t nbig = (size_t)NE*IH/4, nsml = IH/4;
  const size_t total = 3*nbig + 3*nsml;
  for (size_t i = (size_t)blockIdx.x*blockDim.x + threadIdx.x; i < total;
       i += (size_t)gridDim.x*blockDim.x){
    const float4* src; ushort4* dst; size_t j = i;
    if (j < nbig){ src=(const float4*)wg + j;  dst=(ushort4*)wgb + j; }
    else if ((j-=nbig) < nbig){ src=(const float4*)wu + j;  dst=(ushort4*)wub + j; }
    else if ((j-=nbig) < nbig){ src=(const float4*)wd + j;  dst=(ushort4*)wdb + j; }
    else if ((j-=nbig) < nsml){ src=(const float4*)swg + j; dst=(ushort4*)wgb + nbig + j; }
    else if ((j-=nsml) < nsml){ src=(const float4*)swu + j; dst=(ushort4*)wub + nbig + j; }
    else { j-=nsml; src=(const float4*)swd + j; dst=(ushort4*)wdb + nbig + j; }
    float4 f = *src;
    ushort4 o; o.x=f2bf(f.x); o.y=f2bf(f.y); o.z=f2bf(f.z); o.w=f2bf(f.w);
    *dst = o;
  }
}

// ---------------- router: logits + sigmoid + top-4 select (fused) ----------------
__global__ __launch_bounds__(256) void k_logits(const float* __restrict__ x,
                                                const float* __restrict__ gw,
                                                const float* __restrict__ bias,
                                                float* __restrict__ wdense,
                                                u64* __restrict__ maskbits){
  int t = blockIdx.x, tid = threadIdx.x;
  int lane = tid & 63, wv = tid >> 6;
  const float* xr = x + (size_t)t*HD;
  float acc[NE];
  #pragma unroll
  for (int e=0;e<NE;e++) acc[e]=0.f;
  for (int k=tid;k<HD;k+=256){
    float xv = xr[k];
    #pragma unroll
    for (int e=0;e<NE;e++) acc[e] += xv * gw[e*HD + k];
  }
  __shared__ float red[NE][4];
  #pragma unroll
  for (int e=0;e<NE;e++){
    float v = acc[e];
    #pragma unroll
    for (int off=32;off>0;off>>=1) v += __shfl_down(v, off, 64);
    if (lane==0) red[e][wv] = v;
  }
  __syncthreads();
  if (tid == 0){
    float sc[NE], bs[NE];
    #pragma unroll
    for (int e=0;e<NE;e++){
      float l = red[e][0]+red[e][1]+red[e][2]+red[e][3];
      float s = 1.f/(1.f+expf(-l));
      sc[e]=s; bs[e]=s+bias[e];
    }
    int idx[TOPK]; float wsum=0.f; unsigned used=0;
    for (int k=0;k<TOPK;k++){
      int best=0; float bv=-1e30f;
      for (int e=0;e<NE;e++) if (!((used>>e)&1u) && bs[e] > bv){ bv=bs[e]; best=e; }
      used |= 1u<<best; idx[k]=best; wsum += sc[best];
    }
    float inv = 1.f/wsum;
    for (int k=0;k<TOPK;k++){
      int e = idx[k];
      wdense[t*NE + e] = sc[e]*inv;
      atomicOr(&maskbits[e*32 + (t>>6)], 1ull << (t&63));
    }
  }
}

// prefix sums + dense tile table (tiny, 1 thread — deterministic)
__global__ void k_scan(const u64* __restrict__ maskbits, int* __restrict__ counts,
                       int* __restrict__ offsets, int* __restrict__ wordpfx,
                       int* __restrict__ tiles){
  int acc = 0;
  for (int e=0;e<NE;e++){
    int c = 0;
    for (int w=0;w<32;w++){ wordpfx[e*32+w] = c; c += __popcll(maskbits[e*32+w]); }
    counts[e] = c;
  }
  for (int e=0;e<NE;e++){ offsets[e] = acc; acc += counts[e]; }
  offsets[NE] = acc;   // == SLOTS
  counts[NE] = TK;     // shared expert
  int nt = 0;
  for (int g=0; g<NG; g++){
    int c = counts[g];
    for (int mt=0; mt*128 < c && nt < MAXT; mt++) tiles[nt++] = (g<<8) | mt;
  }
  for (; nt<MAXT; nt++) tiles[nt] = -1;
}

// deterministic compaction via popcount rank
__global__ void k_scatter(const u64* __restrict__ maskbits, const int* __restrict__ offsets,
                          const int* __restrict__ wordpfx, const float* __restrict__ wdense,
                          int* __restrict__ rowtok, float* __restrict__ roww){
  int t = blockIdx.x*blockDim.x + threadIdx.x;
  int e = blockIdx.y;
  if (t >= TK) return;
  if (e == NE){ rowtok[offsets[NE]+t] = t; roww[offsets[NE]+t] = 1.f; return; }
  u64 w = maskbits[e*32 + (t>>6)];
  if ((w >> (t&63)) & 1ull){
    int pos = offsets[e] + wordpfx[e*32 + (t>>6)] + __popcll(w & ((1ull << (t&63)) - 1ull));
    rowtok[pos] = t; roww[pos] = wdense[t*NE + e];
  }
}

// ============ GEMM1 (bf16 weights): P = silu(X Wg^T)*(X Wu^T)*roww ============
// BM=128, BN=64 (gate+up), BK=64; tile-table grid (ny, MAXT)
__global__ __launch_bounds__(256) void k_gemm1b(
    const u16* __restrict__ xb, const u16* __restrict__ wgb, const u16* __restrict__ wub,
    const int* __restrict__ counts, const int* __restrict__ offsets,
    const int* __restrict__ rowtok, const float* __restrict__ roww,
    const int* __restrict__ tiles, u16* __restrict__ P)
{
  int te = tiles[blockIdx.y];
  if (te < 0) return;
  int g = te >> 8, mt = te & 255;
  int cnt = counts[g];
  int n0 = blockIdx.x*64;
  int base = offsets[g];
  const u16* wg16 = wgb + (size_t)g*IH;
  const u16* wu16 = wub + (size_t)g*IH;

  __shared__ u16 lsA[128*64];
  __shared__ u16 lsG[64*64];
  __shared__ u16 lsU[64*64];

  int tid = threadIdx.x, lane = tid & 63, wv = tid >> 6;
  int wm = (wv>>1)*64, wn = (wv&1)*32;
  int rl = lane & 15, hi = lane >> 4;

  f32x4 accg[4][2] = {}; f32x4 accu[4][2] = {};

  // staging descriptors (source pre-swizzled: col block = cb ^ (r&7))
  const u16* aSrc[4];
  #pragma unroll
  for (int i=0;i<4;i++){
    int b = i*256 + tid, r = b>>3, cb = b&7;
    int m = mt*128 + r; if (m >= cnt) m = cnt-1;
    int tok = rowtok[base + m];
    aSrc[i] = xb + (size_t)tok*HD + ((cb ^ (r&7))<<3);
  }
  const u16 *gSrc[2], *uSrc[2];
  #pragma unroll
  for (int i=0;i<2;i++){
    int b = i*256 + tid, r = b>>3, cb = b&7;
    size_t off = (size_t)(n0 + r)*HD + ((cb ^ (r&7))<<3);
    gSrc[i] = wg16 + off; uSrc[i] = wu16 + off;
  }

  for (int k0=0; k0<HD; k0+=64){
    #pragma unroll
    for (int i=0;i<4;i++) GLD16(aSrc[i]+k0, lsA + (i*256 + wv*64)*8);
    #pragma unroll
    for (int i=0;i<2;i++) GLD16(gSrc[i]+k0, lsG + (i*256 + wv*64)*8);
    #pragma unroll
    for (int i=0;i<2;i++) GLD16(uSrc[i]+k0, lsU + (i*256 + wv*64)*8);
    __syncthreads();
    #pragma unroll
    for (int ks=0; ks<2; ++ks){
      int off = ks*64 + hi*16;
      s16x8 af[4];
      #pragma unroll
      for (int mi=0;mi<4;mi++) af[mi] = *fragp(lsA, wm+16*mi+rl, off);
      #pragma unroll
      for (int ni=0;ni<2;ni++){
        s16x8 bg = *fragp(lsG, wn+16*ni+rl, off);
        s16x8 bu = *fragp(lsU, wn+16*ni+rl, off);
        #pragma unroll
        for (int mi=0;mi<4;mi++){
          accg[mi][ni] = __builtin_amdgcn_mfma_f32_16x16x32_bf16(af[mi], bg, accg[mi][ni], 0,0,0);
          accu[mi][ni] = __builtin_amdgcn_mfma_f32_16x16x32_bf16(af[mi], bu, accu[mi][ni], 0,0,0);
        }
      }
    }
    __syncthreads();
  }
  // epilogue: SwiGLU * token weight -> bf16 P
  int rl4 = hi*4, cl = rl;
  #pragma unroll
  for (int mi=0;mi<4;mi++){
    #pragma unroll
    for (int j=0;j<4;j++){
      int m = mt*128 + wm + mi*16 + rl4 + j;
      if (m < cnt){
        int slot = base + m;
        float wgt = roww[slot];
        #pragma unroll
        for (int ni=0;ni<2;ni++){
          float gv = accg[mi][ni][j], uv = accu[mi][ni][j];
          float pv = gv/(1.f+expf(-gv))*uv*wgt;
          P[(size_t)slot*ID + n0 + wn + ni*16 + cl] = f2bf(pv);
        }
      }
    }
  }
}

// ============ GEMM2 (bf16 weights): out[tok] += P @ Wd^T ============
// BM=128, BN=128, BK=64; tile-table grid (ny, MAXT)
__global__ __launch_bounds__(256) void k_gemm2b(
    const u16* __restrict__ P, const u16* __restrict__ wdb,
    const int* __restrict__ counts, const int* __restrict__ offsets,
    const int* __restrict__ rowtok, const int* __restrict__ tiles,
    float* __restrict__ out)
{
  int te = tiles[blockIdx.y];
  if (te < 0) return;
  int g = te >> 8, mt = te & 255;
  int cnt = counts[g];
  int n0 = blockIdx.x*128;
  int base = offsets[g];
  const u16* wd16 = wdb + (size_t)g*IH;

  __shared__ u16 lsA[128*64];
  __shared__ u16 lsB[128*64];

  int tid = threadIdx.x, lane = tid & 63, wv = tid >> 6;
  int wm = (wv>>1)*64, wn = (wv&1)*64;
  int rl = lane & 15, hi = lane >> 4;
  f32x4 acc[4][4] = {};

  const u16 *aSrc[4], *bSrc[4];
  #pragma unroll
  for (int i=0;i<4;i++){
    int b = i*256 + tid, r = b>>3, cb = b&7;
    int m = mt*128 + r; if (m >= cnt) m = cnt-1;
    aSrc[i] = P + (size_t)(base + m)*ID + ((cb ^ (r&7))<<3);
    bSrc[i] = wd16 + (size_t)(n0 + r)*ID + ((cb ^ (r&7))<<3);
  }

  for (int k0=0; k0<ID; k0+=64){
    #pragma unroll
    for (int i=0;i<4;i++) GLD16(aSrc[i]+k0, lsA + (i*256 + wv*64)*8);
    #pragma unroll
    for (int i=0;i<4;i++) GLD16(bSrc[i]+k0, lsB + (i*256 + wv*64)*8);
    __syncthreads();
    #pragma unroll
    for (int ks=0; ks<2; ++ks){
      int off = ks*64 + hi*16;
      s16x8 af[4], bf[4];
      #pragma unroll
      for (int mi=0;mi<4;mi++) af[mi] = *fragp(lsA, wm+16*mi+rl, off);
      #pragma unroll
      for (int ni=0;ni<4;ni++) bf[ni] = *fragp(lsB, wn+16*ni+rl, off);
      #pragma unroll
      for (int mi=0;mi<4;mi++)
        #pragma unroll
        for (int ni=0;ni<4;ni++)
          acc[mi][ni] = __builtin_amdgcn_mfma_f32_16x16x32_bf16(af[mi], bf[ni], acc[mi][ni], 0,0,0);
    }
    __syncthreads();
  }
  int rl4 = hi*4, cl = rl;
  #pragma unroll
  for (int mi=0;mi<4;mi++){
    #pragma unroll
    for (int j=0;j<4;j++){
      int m = mt*128 + wm + mi*16 + rl4 + j;
      if (m < cnt){
        int tok = rowtok[base + m];
        #pragma unroll
        for (int ni=0;ni<4;ni++)
          atomicAdd(&out[(size_t)tok*HD + n0 + wn + ni*16 + cl], acc[mi][ni][j]);
      }
    }
  }
}

// ============ fallback kernels (fp32 weights, small ws) ============
__global__ __launch_bounds__(256) void k_gemm1o(
    const u16* __restrict__ xb,
    const float* __restrict__ w_gate, const float* __restrict__ w_up,
    const float* __restrict__ sw_gate, const float* __restrict__ sw_up,
    const int* __restrict__ counts, const int* __restrict__ offsets,
    const int* __restrict__ rowtok, const float* __restrict__ roww,
    const int* __restrict__ tiles, u16* __restrict__ P)
{
  int te = tiles[blockIdx.y];
  if (te < 0) return;
  int g = te >> 8, mt = te & 255;
  int cnt = counts[g];
  int n0 = blockIdx.x*64;
  int base = offsets[g];
  const float* wg32 = (g<NE) ? w_gate + (size_t)g*IH : sw_gate;
  const float* wu32 = (g<NE) ? w_up   + (size_t)g*IH : sw_up;

  __shared__ u16 lsA[128][40];
  __shared__ u16 lsG[64][40];
  __shared__ u16 lsU[64][40];

  int tid = threadIdx.x, lane = tid & 63, wv = tid >> 6;
  int wm = (wv>>1)*64, wn = (wv&1)*32;
  f32x4 accg[4][2] = {}; f32x4 accu[4][2] = {};
  int arow = tid>>1, ahalf = tid&1;
  int am = mt*128 + arow;
  const u16* aptr = nullptr;
  if (am < cnt){ int tok = rowtok[base + am]; aptr = xb + (size_t)tok*HD + 16*ahalf; }

  for (int k0=0; k0<HD; k0+=32){
    uint4 a0 = {0,0,0,0}, a1 = {0,0,0,0};
    if (aptr){ a0 = *(const uint4*)(aptr + k0); a1 = *(const uint4*)(aptr + k0 + 8); }
    *(uint4*)&lsA[arow][16*ahalf]   = a0;
    *(uint4*)&lsA[arow][16*ahalf+8] = a1;
    int r = tid>>2, cg = tid&3;
    {
      const float* s = wg32 + (size_t)(n0+r)*HD + k0 + 8*cg;
      float4 f0 = *(const float4*)s, f1 = *(const float4*)(s+4);
      ushort4 o0, o1;
      o0.x=f2bf(f0.x); o0.y=f2bf(f0.y); o0.z=f2bf(f0.z); o0.w=f2bf(f0.w);
      o1.x=f2bf(f1.x); o1.y=f2bf(f1.y); o1.z=f2bf(f1.z); o1.w=f2bf(f1.w);
      *(ushort4*)&lsG[r][8*cg]   = o0;
      *(ushort4*)&lsG[r][8*cg+4] = o1;
    }
    {
      const float* s = wu32 + (size_t)(n0+r)*HD + k0 + 8*cg;
      float4 f0 = *(const float4*)s, f1 = *(const float4*)(s+4);
      ushort4 o0, o1;
      o0.x=f2bf(f0.x); o0.y=f2bf(f0.y); o0.z=f2bf(f0.z); o0.w=f2bf(f0.w);
      o1.x=f2bf(f1.x); o1.y=f2bf(f1.y); o1.z=f2bf(f1.z); o1.w=f2bf(f1.w);
      *(ushort4*)&lsU[r][8*cg]   = o0;
      *(ushort4*)&lsU[r][8*cg+4] = o1;
    }
    __syncthreads();
    int kb = 8*(lane>>4), rl = lane&15;
    s16x8 af[4];
    #pragma unroll
    for (int mi=0;mi<4;mi++) af[mi] = *(const s16x8*)&lsA[wm+16*mi+rl][kb];
    #pragma unroll
    for (int ni=0;ni<2;ni++){
      s16x8 bg = *(const s16x8*)&lsG[wn+16*ni+rl][kb];
      s16x8 bu = *(const s16x8*)&lsU[wn+16*ni+rl][kb];
      #pragma unroll
      for (int mi=0;mi<4;mi++){
        accg[mi][ni] = __builtin_amdgcn_mfma_f32_16x16x32_bf16(af[mi], bg, accg[mi][ni], 0,0,0);
        accu[mi][ni] = __builtin_amdgcn_mfma_f32_16x16x32_bf16(af[mi], bu, accu[mi][ni], 0,0,0);
      }
    }
    __syncthreads();
  }
  int rl4 = (lane>>4)*4, cl = lane&15;
  #pragma unroll
  for (int mi=0;mi<4;mi++){
    #pragma unroll
    for (int j=0;j<4;j++){
      int m = mt*128 + wm + mi*16 + rl4 + j;
      if (m < cnt){
        int slot = base + m;
        float wgt = roww[slot];
        #pragma unroll
        for (int ni=0;ni<2;ni++){
          float gv = accg[mi][ni][j], uv = accu[mi][ni][j];
          float pv = gv/(1.f+expf(-gv))*uv*wgt;
          P[(size_t)slot*ID + n0 + wn + ni*16 + cl] = f2bf(pv);
        }
      }
    }
  }
}

__global__ __launch_bounds__(256) void k_gemm2o(
    const u16* __restrict__ P,
    const float* __restrict__ w_down, const float* __restrict__ sw_down,
    const int* __restrict__ counts, const int* __restrict__ offsets,
    const int* __restrict__ rowtok, const int* __restrict__ tiles,
    float* __restrict__ out)
{
  int te = tiles[blockIdx.y];
  if (te < 0) return;
  int g = te >> 8, mt = te & 255;
  int cnt = counts[g];
  int n0 = blockIdx.x*128;
  int base = offsets[g];
  const float* wd32 = (g<NE) ? w_down + (size_t)g*IH : sw_down;

  __shared__ u16 lsA[128][40];
  __shared__ u16 lsB[128][40];

  int tid = threadIdx.x, lane = tid & 63, wv = tid >> 6;
  int wm = (wv>>1)*64, wn = (wv&1)*64;
  f32x4 acc[4][4] = {};
  int arow = tid>>1, ahalf = tid&1;
  int am = mt*128 + arow;
  const u16* aptr = (am < cnt) ? P + (size_t)(base+am)*ID + 16*ahalf : nullptr;

  for (int k0=0; k0<ID; k0+=32){
    uint4 a0 = {0,0,0,0}, a1 = {0,0,0,0};
    if (aptr){ a0 = *(const uint4*)(aptr + k0); a1 = *(const uint4*)(aptr + k0 + 8); }
    *(uint4*)&lsA[arow][16*ahalf]   = a0;
    *(uint4*)&lsA[arow][16*ahalf+8] = a1;
    int r = tid>>1, hf = tid&1;
    const float* s = wd32 + (size_t)(n0+r)*ID + k0 + 16*hf;
    float4 f0=*(const float4*)s, f1=*(const float4*)(s+4), f2=*(const float4*)(s+8), f3=*(const float4*)(s+12);
    ushort4 o0,o1,o2,o3;
    o0.x=f2bf(f0.x); o0.y=f2bf(f0.y); o0.z=f2bf(f0.z); o0.w=f2bf(f0.w);
    o1.x=f2bf(f1.x); o1.y=f2bf(f1.y); o1.z=f2bf(f1.z); o1.w=f2bf(f1.w);
    o2.x=f2bf(f2.x); o2.y=f2bf(f2.y); o2.z=f2bf(f2.z); o2.w=f2bf(f2.w);
    o3.x=f2bf(f3.x); o3.y=f2bf(f3.y); o3.z=f2bf(f3.z); o3.w=f2bf(f3.w);
    *(ushort4*)&lsB[r][16*hf]    = o0;
    *(ushort4*)&lsB[r][16*hf+4]  = o1;
    *(ushort4*)&lsB[r][16*hf+8]  = o2;
    *(ushort4*)&lsB[r][16*hf+12] = o3;
    __syncthreads();
    int kb = 8*(lane>>4), rl = lane&15;
    s16x8 af[4], bfr[4];
    #pragma unroll
    for (int mi=0;mi<4;mi++) af[mi]  = *(const s16x8*)&lsA[wm+16*mi+rl][kb];
    #pragma unroll
    for (int ni=0;ni<4;ni++) bfr[ni] = *(const s16x8*)&lsB[wn+16*ni+rl][kb];
    #pragma unroll
    for (int mi=0;mi<4;mi++)
      #pragma unroll
      for (int ni=0;ni<4;ni++)
        acc[mi][ni] = __builtin_amdgcn_mfma_f32_16x16x32_bf16(af[mi], bfr[ni], acc[mi][ni], 0,0,0);
    __syncthreads();
  }
  int rl4 = (lane>>4)*4, cl = lane&15;
  #pragma unroll
  for (int mi=0;mi<4;mi++){
    #pragma unroll
    for (int j=0;j<4;j++){
      int m = mt*128 + wm + mi*16 + rl4 + j;
      if (m < cnt){
        int tok = rowtok[base + m];
        #pragma unroll
        for (int ni=0;ni<4;ni++)
          atomicAdd(&out[(size_t)tok*HD + n0 + wn + ni*16 + cl], acc[mi][ni][j]);
      }
    }
  }
}

// ---------------- host ----------------

extern "C" void kernel_launch(void* const* d_in, const int* in_sizes, int n_in,
                              void* d_out, int out_size, void* d_ws, size_t ws_size,
                              hipStream_t stream){
  (void)in_sizes; (void)n_in;
  const float* x       = (const float*)d_in[0];
  const float* gate_w  = (const float*)d_in[1];
  const float* ebias   = (const float*)d_in[2];
  const float* w_gate  = (const float*)d_in[3];
  const float* w_up    = (const float*)d_in[4];
  const float* w_down  = (const float*)d_in[5];
  const float* sw_gate = (const float*)d_in[6];
  const float* sw_up   = (const float*)d_in[7];
  const float* sw_down = (const float*)d_in[8];
  float* out = (float*)d_out;

  char* p = (char*)d_ws;
  auto alloc = [&](size_t bytes)->char*{ char* r = p; p += (bytes + 255) & ~(size_t)255; return r; };
  u16*   xb       = (u16*)  alloc((size_t)TK*HD*2);
  u16*   P        = (u16*)  alloc((size_t)ROWS_ALL*ID*2);
  float* wdense   = (float*)alloc((size_t)TK*NE*4);
  u64*   maskbits = (u64*)  alloc((size_t)NE*32*8);
  int*   wordpfx  = (int*)  alloc((size_t)NE*32*4);
  int*   counts   = (int*)  alloc(64);
  int*   offsets  = (int*)  alloc(64);
  int*   tiles    = (int*)  alloc(MAXT*4);
  int*   rowtok   = (int*)  alloc((size_t)ROWS_ALL*4);
  float* roww     = (float*)alloc((size_t)ROWS_ALL*4);
  size_t base_end = (size_t)(p - (char*)d_ws);
  size_t slab = (size_t)NG*IH*2;
  bool big = ws_size >= base_end + 3*slab + 4096;
  u16 *wgb=nullptr, *wub=nullptr, *wdb=nullptr;
  if (big){ wgb=(u16*)alloc(slab); wub=(u16*)alloc(slab); wdb=(u16*)alloc(slab); }

  k_prep<<<2048, 256, 0, stream>>>(x, xb, out, out_size, maskbits);
  if (big)
    k_cvtw<<<2048, 256, 0, stream>>>(w_gate, w_up, w_down, sw_gate, sw_up, sw_down,
                                     wgb, wub, wdb);
  k_logits<<<TK, 256, 0, stream>>>(x, gate_w, ebias, wdense, maskbits);
  k_scan<<<1, 1, 0, stream>>>(maskbits, counts, offsets, wordpfx, tiles);
  k_scatter<<<dim3(TK/256, NG), 256, 0, stream>>>(maskbits, offsets, wordpfx, wdense, rowtok, roww);

  dim3 g1(ID/64, MAXT);
  dim3 g2(HD/128, MAXT);
  if (big){
    k_gemm1b<<<g1, 256, 0, stream>>>(xb, wgb, wub, counts, offsets, rowtok, roww, tiles, P);
    k_gemm2b<<<g2, 256, 0, stream>>>(P, wdb, counts, offsets, rowtok, tiles, out);
  } else {
    k_gemm1o<<<g1, 256, 0, stream>>>(xb, w_gate, w_up, sw_gate, sw_up,
                                     counts, offsets, rowtok, roww, tiles, P);
    k_gemm2o<<<g2, 256, 0, stream>>>(P, w_down, sw_down, counts, offsets, rowtok, tiles, out);
  }
}